// Round 1
// baseline (394.523 us; speedup 1.0000x reference)
//
#include <hip/hip_runtime.h>
#include <cstdint>
#include <cstddef>

typedef _Float16 v8h __attribute__((ext_vector_type(8)));
typedef _Float16 v4h __attribute__((ext_vector_type(4)));
typedef float v4f __attribute__((ext_vector_type(4)));

#define NH 16
#define HD 128
#define SLEN 2048
#define BATCH 2
#define HID 2048

// ---------------------------------------------------------------------------
// small prep kernels
// ---------------------------------------------------------------------------

__global__ __launch_bounds__(256) void cast_x_kernel(const float* __restrict__ in,
                                                     _Float16* __restrict__ out, int n4) {
  int i = blockIdx.x * 256 + threadIdx.x;
  if (i >= n4) return;
  const float4 v = ((const float4*)in)[i];
  v4h o; o[0] = (_Float16)v.x; o[1] = (_Float16)v.y; o[2] = (_Float16)v.z; o[3] = (_Float16)v.w;
  *(v4h*)(out + (size_t)i * 4) = o;
}

// W [R][C] fp32 -> WT [C][R] f16
__global__ __launch_bounds__(256) void transpose_cast_kernel(const float* __restrict__ W,
                                                             _Float16* __restrict__ WT,
                                                             int R, int C) {
  __shared__ float tl[32][33];
  int tx = threadIdx.x, ty = threadIdx.y;
  int c0 = blockIdx.x * 32, r0 = blockIdx.y * 32;
#pragma unroll
  for (int i = 0; i < 4; ++i)
    tl[ty + i * 8][tx] = W[(size_t)(r0 + ty + i * 8) * C + c0 + tx];
  __syncthreads();
#pragma unroll
  for (int i = 0; i < 4; ++i)
    WT[(size_t)(c0 + ty + i * 8) * R + r0 + tx] = (_Float16)tl[tx][ty + i * 8];
}

// V [bh][S][HD] f16 -> VT [bh][HD][S] f16
__global__ __launch_bounds__(256) void transpose_v_kernel(const _Float16* __restrict__ V,
                                                          _Float16* __restrict__ VT) {
  __shared__ _Float16 tl[32][33];
  int tx = threadIdx.x, ty = threadIdx.y;
  int s0 = blockIdx.x * 32, d0 = blockIdx.y * 32;
  int bh = blockIdx.z;
  const _Float16* Vp = V + (size_t)bh * SLEN * HD;
  _Float16* Tp = VT + (size_t)bh * HD * SLEN;
#pragma unroll
  for (int i = 0; i < 4; ++i)
    tl[ty + i * 8][tx] = Vp[(size_t)(s0 + ty + i * 8) * HD + d0 + tx];
  __syncthreads();
#pragma unroll
  for (int i = 0; i < 4; ++i)
    Tp[(size_t)(d0 + ty + i * 8) * SLEN + s0 + tx] = tl[tx][ty + i * 8];
}

__global__ void rope_table_kernel(float* __restrict__ cost, float* __restrict__ sint) {
  int s = blockIdx.x, i = threadIdx.x;  // 2048 blocks x 64 threads
  float inv = powf(10000.0f, -(float)i * (1.0f / 64.0f));
  float ang = (float)s * inv;
  cost[s * 64 + i] = cosf(ang);
  sint[s * 64 + i] = sinf(ang);
}

// in-place GPT-NeoX rope on Q and K, layout [bh][S][HD]
__global__ __launch_bounds__(256) void rope_apply_kernel(_Float16* __restrict__ Q,
                                                         _Float16* __restrict__ K,
                                                         const float* __restrict__ cost,
                                                         const float* __restrict__ sint) {
  int idx = blockIdx.x * 256 + threadIdx.x;  // [0, 32*2048*64)
  int d = idx & 63;
  int s = (idx >> 6) & (SLEN - 1);
  int bh = idx >> 17;
  size_t base = ((size_t)bh * SLEN + s) * HD;
  float c = cost[s * 64 + d], sn = sint[s * 64 + d];
  {
    float a = (float)Q[base + d], b = (float)Q[base + d + 64];
    Q[base + d] = (_Float16)(a * c - b * sn);
    Q[base + d + 64] = (_Float16)(b * c + a * sn);
  }
  {
    float a = (float)K[base + d], b = (float)K[base + d + 64];
    K[base + d] = (_Float16)(a * c - b * sn);
    K[base + d + 64] = (_Float16)(b * c + a * sn);
  }
}

// ---------------------------------------------------------------------------
// GEMM: C[M,N] = A[M,K] * B[K,N], with B given transposed (BT [N][K]), f16 in,
// fp32 accum. MODE 0: QKV epilogue (route q/k/v per head, f16 out).
// MODE 1: plain fp32 store to f_out.
// Tile 128x128, BK=64, 4 waves each 64x64. XOR-swizzled LDS.
// ---------------------------------------------------------------------------
template <int MODE>
__global__ __launch_bounds__(256) void gemm_kernel(const _Float16* __restrict__ A,
                                                   const _Float16* __restrict__ BT,
                                                   int M, int N, int K,
                                                   _Float16* __restrict__ q_out,
                                                   _Float16* __restrict__ k_out,
                                                   _Float16* __restrict__ v_out,
                                                   float* __restrict__ f_out) {
  __shared__ alignas(16) char As[128 * 128];  // 128 rows x 64 f16 (swizzled)
  __shared__ alignas(16) char Bs[128 * 128];
  const int t = threadIdx.x;
  const int w = t >> 6;
  const int l = t & 63;
  const int wr = w >> 1, wc = w & 1;
  const int m0 = blockIdx.y * 128;
  const int n0 = blockIdx.x * 128;

  const v4f vzero = {0.f, 0.f, 0.f, 0.f};
  v4f acc[4][4];
#pragma unroll
  for (int mi = 0; mi < 4; ++mi)
#pragma unroll
    for (int ni = 0; ni < 4; ++ni) acc[mi][ni] = vzero;

  for (int k0 = 0; k0 < K; k0 += 64) {
#pragma unroll
    for (int c = 0; c < 4; ++c) {
      int idx = (c * 256 + t) * 8;
      int row = idx >> 6;
      int col = idx & 63;
      uint4 va = *(const uint4*)(A + (size_t)(m0 + row) * K + k0 + col);
      *(uint4*)(As + row * 128 + ((col * 2) ^ ((row & 7) << 4))) = va;
      uint4 vb = *(const uint4*)(BT + (size_t)(n0 + row) * K + k0 + col);
      *(uint4*)(Bs + row * 128 + ((col * 2) ^ ((row & 7) << 4))) = vb;
    }
    __syncthreads();
#pragma unroll
    for (int kk = 0; kk < 2; ++kk) {
      v8h a[4], b[4];
#pragma unroll
      for (int mi = 0; mi < 4; ++mi) {
        int row = wr * 64 + mi * 16 + (l & 15);
        a[mi] = *(const v8h*)(As + row * 128 + ((kk * 64 + ((l >> 4) * 16)) ^ ((row & 7) << 4)));
      }
#pragma unroll
      for (int ni = 0; ni < 4; ++ni) {
        int row = wc * 64 + ni * 16 + (l & 15);
        b[ni] = *(const v8h*)(Bs + row * 128 + ((kk * 64 + ((l >> 4) * 16)) ^ ((row & 7) << 4)));
      }
#pragma unroll
      for (int mi = 0; mi < 4; ++mi)
#pragma unroll
        for (int ni = 0; ni < 4; ++ni)
          acc[mi][ni] = __builtin_amdgcn_mfma_f32_16x16x32_f16(a[mi], b[ni], acc[mi][ni], 0, 0, 0);
    }
    __syncthreads();
  }

#pragma unroll
  for (int mi = 0; mi < 4; ++mi) {
#pragma unroll
    for (int ni = 0; ni < 4; ++ni) {
      int n = n0 + wc * 64 + ni * 16 + (l & 15);
#pragma unroll
      for (int r = 0; r < 4; ++r) {
        int m = m0 + wr * 64 + mi * 16 + (l >> 4) * 4 + r;
        float v = acc[mi][ni][r];
        if (MODE == 1) {
          f_out[(size_t)m * N + n] = v;
        } else {
          int head = n / 384;
          int rem = n - head * 384;
          int seg = rem >> 7;
          int d = rem & 127;
          int s = m >> 1, bb = m & 1;
          _Float16* dst = (seg == 0) ? q_out : (seg == 1) ? k_out : v_out;
          dst[(((size_t)(bb * NH + head)) * SLEN + s) * HD + d] = (_Float16)v;
        }
      }
    }
  }
}

// ---------------------------------------------------------------------------
// Flash attention (causal). Q,K: [bh][S][HD] f16 (rope'd), VT: [bh][HD][S] f16.
// Block: 64 Q rows (4 waves x 16), loop KV tiles of 64. Online softmax fp32.
// Output ctx [(s*B+b)][HID] f16.
// ---------------------------------------------------------------------------
__global__ __launch_bounds__(256) void attn_kernel(const _Float16* __restrict__ Qb,
                                                   const _Float16* __restrict__ Kb,
                                                   const _Float16* __restrict__ VTb,
                                                   _Float16* __restrict__ ctx) {
  __shared__ alignas(16) char Ks[64 * 256];   // 64 keys x 128 d (swizzled rows of 256B)
  __shared__ alignas(16) char Vs[128 * 128];  // 128 d x 64 keys (swizzled rows of 128B)
  __shared__ alignas(16) char Ps[4 * 2048];   // per-wave 16 x 64 f16 (swizzled)
  const int t = threadIdx.x;
  const int w = t >> 6;
  const int l = t & 63;
  const int bh = blockIdx.y;
  const int q0 = blockIdx.x * 64;

  const _Float16* Qp = Qb + (size_t)bh * SLEN * HD;
  const _Float16* Kp = Kb + (size_t)bh * SLEN * HD;
  const _Float16* Vp = VTb + (size_t)bh * HD * SLEN;

  // hoist Q fragments into registers
  v8h qf[4];
  {
    int qrow = q0 + w * 16 + (l & 15);
#pragma unroll
    for (int kk = 0; kk < 4; ++kk)
      qf[kk] = *(const v8h*)(Qp + (size_t)qrow * HD + kk * 32 + (l >> 4) * 8);
  }

  const v4f vzero = {0.f, 0.f, 0.f, 0.f};
  v4f o[8];
#pragma unroll
  for (int df = 0; df < 8; ++df) o[df] = vzero;
  float mreg[4], lreg[4];
#pragma unroll
  for (int r = 0; r < 4; ++r) { mreg[r] = -1e30f; lreg[r] = 0.f; }

  const float scale = 0.08838834764831845f;  // 1/sqrt(128)
  const int nkv = blockIdx.x + 1;

  for (int kt = 0; kt < nkv; ++kt) {
    const int kv0 = kt * 64;
    // stage K tile [64][128] and VT tile [128][64]
#pragma unroll
    for (int c = 0; c < 4; ++c) {
      int idx = (c * 256 + t) * 8;
      {
        int row = idx >> 7, col = idx & 127;
        uint4 v = *(const uint4*)(Kp + (size_t)(kv0 + row) * HD + col);
        *(uint4*)(Ks + row * 256 + ((col * 2) ^ ((row & 7) << 4))) = v;
      }
      {
        int dd = idx >> 6, key = idx & 63;
        uint4 v = *(const uint4*)(Vp + (size_t)dd * SLEN + kv0 + key);
        *(uint4*)(Vs + dd * 128 + ((key * 2) ^ ((dd & 7) << 4))) = v;
      }
    }
    __syncthreads();

    // S = Q K^T
    v4f sacc[4];
#pragma unroll
    for (int nf = 0; nf < 4; ++nf) sacc[nf] = vzero;
#pragma unroll
    for (int nf = 0; nf < 4; ++nf) {
      int krow = nf * 16 + (l & 15);
#pragma unroll
      for (int kk = 0; kk < 4; ++kk) {
        v8h kf = *(const v8h*)(Ks + krow * 256 +
                               ((kk * 64 + ((l >> 4) * 16)) ^ ((krow & 7) << 4)));
        sacc[nf] = __builtin_amdgcn_mfma_f32_16x16x32_f16(qf[kk], kf, sacc[nf], 0, 0, 0);
      }
    }

    // scale + causal mask (only diagonal tile needs it)
    const bool diag = (kv0 == q0);
#pragma unroll
    for (int nf = 0; nf < 4; ++nf) {
#pragma unroll
      for (int r = 0; r < 4; ++r) {
        float s = sacc[nf][r] * scale;
        if (diag) {
          int qg = q0 + w * 16 + (l >> 4) * 4 + r;
          int kg = kv0 + nf * 16 + (l & 15);
          if (kg > qg) s = -1e4f;
        }
        sacc[nf][r] = s;
      }
    }

    // online softmax stats (rows live across 16 lanes of each quarter-wave)
    float alpha[4];
#pragma unroll
    for (int r = 0; r < 4; ++r) {
      float mv = fmaxf(fmaxf(sacc[0][r], sacc[1][r]), fmaxf(sacc[2][r], sacc[3][r]));
#pragma unroll
      for (int off = 1; off < 16; off <<= 1) mv = fmaxf(mv, __shfl_xor(mv, off));
      float mnew = fmaxf(mreg[r], mv);
      alpha[r] = __expf(mreg[r] - mnew);
      mreg[r] = mnew;
      float rs = 0.f;
#pragma unroll
      for (int nf = 0; nf < 4; ++nf) {
        float p = __expf(sacc[nf][r] - mnew);
        sacc[nf][r] = p;
        rs += p;
      }
#pragma unroll
      for (int off = 1; off < 16; off <<= 1) rs += __shfl_xor(rs, off);
      lreg[r] = lreg[r] * alpha[r] + rs;
    }

    // write P (f16) to per-wave LDS, C-layout -> A-layout transpose
    char* Pw = Ps + w * 2048;
#pragma unroll
    for (int nf = 0; nf < 4; ++nf) {
      int key = nf * 16 + (l & 15);
#pragma unroll
      for (int r = 0; r < 4; ++r) {
        int pr = (l >> 4) * 4 + r;
        *(_Float16*)(Pw + pr * 128 + ((key * 2) ^ ((pr & 7) << 4))) = (_Float16)sacc[nf][r];
      }
    }
    asm volatile("s_waitcnt lgkmcnt(0)" ::: "memory");
    __builtin_amdgcn_sched_barrier(0);

    // rescale O
#pragma unroll
    for (int df = 0; df < 8; ++df)
#pragma unroll
      for (int r = 0; r < 4; ++r) o[df][r] *= alpha[r];

    // O += P * V
#pragma unroll
    for (int kk2 = 0; kk2 < 2; ++kk2) {
      int pr = l & 15;
      v8h pa = *(const v8h*)(Pw + pr * 128 +
                             ((kk2 * 64 + ((l >> 4) * 16)) ^ ((pr & 7) << 4)));
#pragma unroll
      for (int df = 0; df < 8; ++df) {
        int dd = df * 16 + (l & 15);
        v8h vf = *(const v8h*)(Vs + dd * 128 +
                               ((kk2 * 64 + ((l >> 4) * 16)) ^ ((dd & 7) << 4)));
        o[df] = __builtin_amdgcn_mfma_f32_16x16x32_f16(pa, vf, o[df], 0, 0, 0);
      }
    }
    __syncthreads();
  }

  // epilogue: normalize and write ctx [(s*B+b)][h*128+d]
  const int b = bh >> 4;
  const int h = bh & 15;
#pragma unroll
  for (int df = 0; df < 8; ++df) {
    int dd = df * 16 + (l & 15);
#pragma unroll
    for (int r = 0; r < 4; ++r) {
      int s = q0 + w * 16 + (l >> 4) * 4 + r;
      float val = o[df][r] / lreg[r];
      ctx[((size_t)(s * BATCH + b)) * HID + h * HD + dd] = (_Float16)val;
    }
  }
}

// ---------------------------------------------------------------------------

extern "C" void kernel_launch(void* const* d_in, const int* in_sizes, int n_in,
                              void* d_out, int out_size, void* d_ws, size_t ws_size,
                              hipStream_t stream) {
  const float* x = (const float*)d_in[0];
  const float* w_qkv = (const float*)d_in[1];
  const float* w_dense = (const float*)d_in[2];
  float* out = (float*)d_out;
  char* ws = (char*)d_ws;

  _Float16* xb    = (_Float16*)(ws);               // 4096x2048        16 MB
  _Float16* wqkvT = (_Float16*)(ws + 16777216);    // 6144x2048        24 MB
  _Float16* wdT   = (_Float16*)(ws + 41943040);    // 2048x2048         8 MB
  _Float16* Qb    = (_Float16*)(ws + 50331648);    // [32][2048][128]  16 MB
  _Float16* Kb    = (_Float16*)(ws + 67108864);    // [32][2048][128]  16 MB
  _Float16* Vb    = (_Float16*)(ws + 83886080);    // [32][2048][128]  16 MB
  _Float16* VTb   = (_Float16*)(ws + 100663296);   // [32][128][2048]  16 MB
  _Float16* ctx   = (_Float16*)(ws + 117440512);   // 4096x2048        16 MB
  float* cost     = (float*)(ws + 134217728);      // 2048x64 fp32
  float* sint     = (float*)(ws + 134742016);      // 2048x64 fp32

  cast_x_kernel<<<dim3(8192), dim3(256), 0, stream>>>(x, xb, 2097152);
  transpose_cast_kernel<<<dim3(192, 64), dim3(32, 8), 0, stream>>>(w_qkv, wqkvT, 2048, 6144);
  transpose_cast_kernel<<<dim3(64, 64), dim3(32, 8), 0, stream>>>(w_dense, wdT, 2048, 2048);
  rope_table_kernel<<<dim3(2048), dim3(64), 0, stream>>>(cost, sint);

  gemm_kernel<0><<<dim3(48, 32), dim3(256), 0, stream>>>(xb, wqkvT, 4096, 6144, 2048,
                                                         Qb, Kb, Vb, (float*)nullptr);
  rope_apply_kernel<<<dim3(16384), dim3(256), 0, stream>>>(Qb, Kb, cost, sint);
  transpose_v_kernel<<<dim3(64, 4, 32), dim3(32, 8), 0, stream>>>(Vb, VTb);
  attn_kernel<<<dim3(32, 32), dim3(256), 0, stream>>>(Qb, Kb, VTb, ctx);
  gemm_kernel<1><<<dim3(16, 32), dim3(256), 0, stream>>>(ctx, wdT, 4096, 2048, 2048,
                                                         (_Float16*)nullptr, (_Float16*)nullptr,
                                                         (_Float16*)nullptr, out);
}

// Round 2
// 346.148 us; speedup vs baseline: 1.1398x; 1.1398x over previous
//
#include <hip/hip_runtime.h>
#include <cstdint>
#include <cstddef>

typedef _Float16 v8h __attribute__((ext_vector_type(8)));
typedef _Float16 v4h __attribute__((ext_vector_type(4)));
typedef float v4f __attribute__((ext_vector_type(4)));

#define NH 16
#define HD 128
#define SLEN 2048
#define BATCH 2
#define HID 2048

// async global->LDS, 16B per lane. LDS dest is wave-uniform base + lane*16.
__device__ __forceinline__ void gload16(const void* gptr, void* lptr) {
  __builtin_amdgcn_global_load_lds(
      (const __attribute__((address_space(1))) unsigned int*)gptr,
      (__attribute__((address_space(3))) unsigned int*)lptr, 16, 0, 0);
}

// ---------------------------------------------------------------------------
// small prep kernels
// ---------------------------------------------------------------------------

__global__ __launch_bounds__(256) void cast_x_kernel(const float* __restrict__ in,
                                                     _Float16* __restrict__ out, int n4) {
  int i = blockIdx.x * 256 + threadIdx.x;
  if (i >= n4) return;
  const float4 v = ((const float4*)in)[i];
  v4h o; o[0] = (_Float16)v.x; o[1] = (_Float16)v.y; o[2] = (_Float16)v.z; o[3] = (_Float16)v.w;
  *(v4h*)(out + (size_t)i * 4) = o;
}

// W [R][C] fp32 -> WT [C][R] f16
__global__ __launch_bounds__(256) void transpose_cast_kernel(const float* __restrict__ W,
                                                             _Float16* __restrict__ WT,
                                                             int R, int C) {
  __shared__ float tl[32][33];
  int tx = threadIdx.x, ty = threadIdx.y;
  int c0 = blockIdx.x * 32, r0 = blockIdx.y * 32;
#pragma unroll
  for (int i = 0; i < 4; ++i)
    tl[ty + i * 8][tx] = W[(size_t)(r0 + ty + i * 8) * C + c0 + tx];
  __syncthreads();
#pragma unroll
  for (int i = 0; i < 4; ++i)
    WT[(size_t)(c0 + ty + i * 8) * R + r0 + tx] = (_Float16)tl[tx][ty + i * 8];
}

// V [bh][S][HD] f16 -> VT [bh][HD][S] f16
__global__ __launch_bounds__(256) void transpose_v_kernel(const _Float16* __restrict__ V,
                                                          _Float16* __restrict__ VT) {
  __shared__ _Float16 tl[32][33];
  int tx = threadIdx.x, ty = threadIdx.y;
  int s0 = blockIdx.x * 32, d0 = blockIdx.y * 32;
  int bh = blockIdx.z;
  const _Float16* Vp = V + (size_t)bh * SLEN * HD;
  _Float16* Tp = VT + (size_t)bh * HD * SLEN;
#pragma unroll
  for (int i = 0; i < 4; ++i)
    tl[ty + i * 8][tx] = Vp[(size_t)(s0 + ty + i * 8) * HD + d0 + tx];
  __syncthreads();
#pragma unroll
  for (int i = 0; i < 4; ++i)
    Tp[(size_t)(d0 + ty + i * 8) * SLEN + s0 + tx] = tl[tx][ty + i * 8];
}

__global__ void rope_table_kernel(float* __restrict__ cost, float* __restrict__ sint) {
  int s = blockIdx.x, i = threadIdx.x;  // 2048 blocks x 64 threads
  float inv = powf(10000.0f, -(float)i * (1.0f / 64.0f));
  float ang = (float)s * inv;
  cost[s * 64 + i] = cosf(ang);
  sint[s * 64 + i] = sinf(ang);
}

// in-place GPT-NeoX rope on Q and K, layout [bh][S][HD]
__global__ __launch_bounds__(256) void rope_apply_kernel(_Float16* __restrict__ Q,
                                                         _Float16* __restrict__ K,
                                                         const float* __restrict__ cost,
                                                         const float* __restrict__ sint) {
  int idx = blockIdx.x * 256 + threadIdx.x;  // [0, 32*2048*64)
  int d = idx & 63;
  int s = (idx >> 6) & (SLEN - 1);
  int bh = idx >> 17;
  size_t base = ((size_t)bh * SLEN + s) * HD;
  float c = cost[s * 64 + d], sn = sint[s * 64 + d];
  {
    float a = (float)Q[base + d], b = (float)Q[base + d + 64];
    Q[base + d] = (_Float16)(a * c - b * sn);
    Q[base + d + 64] = (_Float16)(b * c + a * sn);
  }
  {
    float a = (float)K[base + d], b = (float)K[base + d + 64];
    K[base + d] = (_Float16)(a * c - b * sn);
    K[base + d + 64] = (_Float16)(b * c + a * sn);
  }
}

// ---------------------------------------------------------------------------
// GEMM: C[M,N] = A[M,K] * B[K,N] with BT [N][K] given. f16 in, fp32 accum.
// 128x128 tile, BK=64, 4 waves, double-buffered global_load_lds staging with
// inverse-swizzled per-lane sources (linear LDS dest, XOR-swizzled reads),
// one barrier per K-step. 1D grid with XCD-chunked decode.
// MODE 0: QKV epilogue routing q/k/v per head (f16). MODE 1: fp32 store.
// ---------------------------------------------------------------------------
template <int MODE>
__global__ __launch_bounds__(256) void gemm_kernel(const _Float16* __restrict__ A,
                                                   const _Float16* __restrict__ BT,
                                                   int M, int N, int K, int gy,
                                                   _Float16* __restrict__ q_out,
                                                   _Float16* __restrict__ k_out,
                                                   _Float16* __restrict__ v_out,
                                                   float* __restrict__ f_out) {
  __shared__ alignas(16) char As[2][16384];
  __shared__ alignas(16) char Bs[2][16384];
  const int t = threadIdx.x;
  const int w = t >> 6;
  const int l = t & 63;
  const int wr = w >> 1, wc = w & 1;

  const int total = gridDim.x;
  const int F = blockIdx.x;
  const int gid = (F & 7) * (total >> 3) + (F >> 3);
  const int bx = gid / gy, by = gid % gy;
  const int m0 = by * 128;
  const int n0 = bx * 128;

  // per-lane inverse-swizzled staging sources (tile [128 rows][64 f16])
  const char* aS[4];
  const char* bS[4];
  {
    const int Kb = K * 2;
#pragma unroll
    for (int j = 0; j < 4; ++j) {
      int c = w * 256 + j * 64 + l;
      int row = c >> 3;
      int col = ((c & 7) * 16) ^ ((row & 7) << 4);
      aS[j] = (const char*)A + (size_t)(m0 + row) * Kb + col;
      bS[j] = (const char*)BT + (size_t)(n0 + row) * Kb + col;
    }
  }

  const v4f vzero = {0.f, 0.f, 0.f, 0.f};
  v4f acc[4][4];
#pragma unroll
  for (int mi = 0; mi < 4; ++mi)
#pragma unroll
    for (int ni = 0; ni < 4; ++ni) acc[mi][ni] = vzero;

  auto stage = [&](int ks, int d) {
#pragma unroll
    for (int j = 0; j < 4; ++j) {
      gload16(aS[j] + ks * 128, &As[d][w * 4096 + j * 1024]);
      gload16(bS[j] + ks * 128, &Bs[d][w * 4096 + j * 1024]);
    }
  };

  const int nk = K >> 6;
  stage(0, 0);
  for (int ks = 0; ks < nk; ++ks) {
    asm volatile("s_waitcnt vmcnt(0)" ::: "memory");
    __syncthreads();
    if (ks + 1 < nk) stage(ks + 1, (ks + 1) & 1);
    const char* Ap = As[ks & 1];
    const char* Bp = Bs[ks & 1];
#pragma unroll
    for (int kk = 0; kk < 2; ++kk) {
      v8h a[4], b[4];
#pragma unroll
      for (int mi = 0; mi < 4; ++mi) {
        int row = wr * 64 + mi * 16 + (l & 15);
        a[mi] = *(const v8h*)(Ap + row * 128 + ((kk * 64 + ((l >> 4) * 16)) ^ ((row & 7) << 4)));
      }
#pragma unroll
      for (int ni = 0; ni < 4; ++ni) {
        int row = wc * 64 + ni * 16 + (l & 15);
        b[ni] = *(const v8h*)(Bp + row * 128 + ((kk * 64 + ((l >> 4) * 16)) ^ ((row & 7) << 4)));
      }
#pragma unroll
      for (int mi = 0; mi < 4; ++mi)
#pragma unroll
        for (int ni = 0; ni < 4; ++ni)
          acc[mi][ni] = __builtin_amdgcn_mfma_f32_16x16x32_f16(a[mi], b[ni], acc[mi][ni], 0, 0, 0);
    }
  }

#pragma unroll
  for (int mi = 0; mi < 4; ++mi) {
#pragma unroll
    for (int ni = 0; ni < 4; ++ni) {
      int n = n0 + wc * 64 + ni * 16 + (l & 15);
#pragma unroll
      for (int r = 0; r < 4; ++r) {
        int m = m0 + wr * 64 + mi * 16 + (l >> 4) * 4 + r;
        float v = acc[mi][ni][r];
        if (MODE == 1) {
          f_out[(size_t)m * N + n] = v;
        } else {
          int head = n / 384;
          int rem = n - head * 384;
          int seg = rem >> 7;
          int d = rem & 127;
          int s = m >> 1, bb = m & 1;
          _Float16* dst = (seg == 0) ? q_out : (seg == 1) ? k_out : v_out;
          dst[(((size_t)(bb * NH + head)) * SLEN + s) * HD + d] = (_Float16)v;
        }
      }
    }
  }
}

// ---------------------------------------------------------------------------
// Flash attention (causal), load-balanced: block handles q-tiles (pr, 31-pr),
// sharing staged K/V. Q,K: [bh][S][HD] f16 (rope'd), VT: [bh][HD][S] f16.
// 4 waves, KVBLK=64, double-buffered global_load_lds staging, 1 barrier/iter.
// blockIdx%8 pins bh&7 -> XCD for K/V L2 locality.
// ---------------------------------------------------------------------------
__global__ __launch_bounds__(256) void attn_kernel(const _Float16* __restrict__ Qb,
                                                   const _Float16* __restrict__ Kb,
                                                   const _Float16* __restrict__ VTb,
                                                   _Float16* __restrict__ ctx) {
  __shared__ alignas(16) char Ks[2][16384];  // [64 keys][128 d] swizzled rows of 256B
  __shared__ alignas(16) char Vs[2][16384];  // [128 d][64 keys] swizzled rows of 128B
  __shared__ alignas(16) char Ps[4 * 2048];  // per-wave 16 x 64 f16 (swizzled)
  const int t = threadIdx.x;
  const int w = t >> 6;
  const int l = t & 63;
  const int F = blockIdx.x;                  // [0,512)
  const int bh = (F & 7) + 8 * ((F >> 3) & 3);
  const int pr = F >> 5;                     // pair index 0..15
  const int ta = pr, tb = 31 - pr;

  const _Float16* Qp = Qb + (size_t)bh * SLEN * HD;
  const _Float16* Kp = Kb + (size_t)bh * SLEN * HD;
  const _Float16* Vp = VTb + (size_t)bh * HD * SLEN;

  // per-lane inverse-swizzled staging sources
  const char* kS[4];
  const char* vS[4];
#pragma unroll
  for (int j = 0; j < 4; ++j) {
    int c = w * 256 + j * 64 + l;
    {
      int row = c >> 4;
      int col = ((c & 15) * 16) ^ ((row & 7) << 4);
      kS[j] = (const char*)Kp + (size_t)row * 256 + col;
    }
    {
      int row = c >> 3;
      int col = ((c & 7) * 16) ^ ((row & 7) << 4);
      vS[j] = (const char*)Vp + (size_t)row * (SLEN * 2) + col;
    }
  }
  auto stage = [&](int kt, int d) {
#pragma unroll
    for (int j = 0; j < 4; ++j) {
      gload16(kS[j] + (size_t)kt * 16384, &Ks[d][w * 4096 + j * 1024]);
      gload16(vS[j] + (size_t)kt * 128, &Vs[d][w * 4096 + j * 1024]);
    }
  };

  // hoist Q fragments for both tiles
  v8h qA[4], qB[4];
  {
    int rA = ta * 64 + w * 16 + (l & 15);
    int rB = tb * 64 + w * 16 + (l & 15);
#pragma unroll
    for (int kk = 0; kk < 4; ++kk) {
      qA[kk] = *(const v8h*)(Qp + (size_t)rA * HD + kk * 32 + (l >> 4) * 8);
      qB[kk] = *(const v8h*)(Qp + (size_t)rB * HD + kk * 32 + (l >> 4) * 8);
    }
  }

  const v4f vzero = {0.f, 0.f, 0.f, 0.f};
  v4f oA[8], oB[8];
#pragma unroll
  for (int df = 0; df < 8; ++df) { oA[df] = vzero; oB[df] = vzero; }
  float mA[4], lA[4], mB[4], lB[4];
#pragma unroll
  for (int r = 0; r < 4; ++r) { mA[r] = -1e30f; lA[r] = 0.f; mB[r] = -1e30f; lB[r] = 0.f; }

  char* Pw = Ps + w * 2048;
  const float scale = 0.08838834764831845f;  // 1/sqrt(128)

  auto process = [&](const v8h* qf, v4f (&o)[8], float (&mreg)[4], float (&lreg)[4],
                     int qt, int kt, const char* Kst, const char* Vst) {
    // S = Q K^T
    v4f sacc[4];
#pragma unroll
    for (int nf = 0; nf < 4; ++nf) sacc[nf] = vzero;
#pragma unroll
    for (int nf = 0; nf < 4; ++nf) {
      int krow = nf * 16 + (l & 15);
#pragma unroll
      for (int kk = 0; kk < 4; ++kk) {
        v8h kf = *(const v8h*)(Kst + krow * 256 +
                               ((kk * 64 + ((l >> 4) * 16)) ^ ((krow & 7) << 4)));
        sacc[nf] = __builtin_amdgcn_mfma_f32_16x16x32_f16(qf[kk], kf, sacc[nf], 0, 0, 0);
      }
    }

    // scale + causal mask (diagonal tile only)
    const bool diag = (kt == qt);
#pragma unroll
    for (int nf = 0; nf < 4; ++nf) {
#pragma unroll
      for (int r = 0; r < 4; ++r) {
        float s = sacc[nf][r] * scale;
        if (diag) {
          int qg = qt * 64 + w * 16 + (l >> 4) * 4 + r;
          int kg = kt * 64 + nf * 16 + (l & 15);
          if (kg > qg) s = -1e4f;
        }
        sacc[nf][r] = s;
      }
    }

    // online softmax (rows across 16 lanes of each quarter-wave)
    float alpha[4];
#pragma unroll
    for (int r = 0; r < 4; ++r) {
      float mv = fmaxf(fmaxf(sacc[0][r], sacc[1][r]), fmaxf(sacc[2][r], sacc[3][r]));
#pragma unroll
      for (int off = 1; off < 16; off <<= 1) mv = fmaxf(mv, __shfl_xor(mv, off));
      float mnew = fmaxf(mreg[r], mv);
      alpha[r] = __expf(mreg[r] - mnew);
      mreg[r] = mnew;
      float rs = 0.f;
#pragma unroll
      for (int nf = 0; nf < 4; ++nf) {
        float p = __expf(sacc[nf][r] - mnew);
        sacc[nf][r] = p;
        rs += p;
      }
#pragma unroll
      for (int off = 1; off < 16; off <<= 1) rs += __shfl_xor(rs, off);
      lreg[r] = lreg[r] * alpha[r] + rs;
    }

    // P (f16) -> per-wave LDS (C-layout -> A-layout transpose)
#pragma unroll
    for (int nf = 0; nf < 4; ++nf) {
      int key = nf * 16 + (l & 15);
#pragma unroll
      for (int r = 0; r < 4; ++r) {
        int prow = (l >> 4) * 4 + r;
        *(_Float16*)(Pw + prow * 128 + ((key * 2) ^ ((prow & 7) << 4))) = (_Float16)sacc[nf][r];
      }
    }
    asm volatile("s_waitcnt lgkmcnt(0)" ::: "memory");
    __builtin_amdgcn_sched_barrier(0);

    // rescale O
#pragma unroll
    for (int df = 0; df < 8; ++df)
#pragma unroll
      for (int r = 0; r < 4; ++r) o[df][r] *= alpha[r];

    // O += P * V
#pragma unroll
    for (int kk2 = 0; kk2 < 2; ++kk2) {
      int prow = l & 15;
      v8h pa = *(const v8h*)(Pw + prow * 128 +
                             ((kk2 * 64 + ((l >> 4) * 16)) ^ ((prow & 7) << 4)));
#pragma unroll
      for (int df = 0; df < 8; ++df) {
        int dd = df * 16 + (l & 15);
        v8h vf = *(const v8h*)(Vst + dd * 128 +
                               ((kk2 * 64 + ((l >> 4) * 16)) ^ ((dd & 7) << 4)));
        o[df] = __builtin_amdgcn_mfma_f32_16x16x32_f16(pa, vf, o[df], 0, 0, 0);
      }
    }
  };

  stage(0, 0);
  for (int kt = 0; kt <= tb; ++kt) {
    asm volatile("s_waitcnt vmcnt(0)" ::: "memory");
    __syncthreads();
    if (kt < tb) stage(kt + 1, (kt + 1) & 1);
    const char* Kst = Ks[kt & 1];
    const char* Vst = Vs[kt & 1];
    if (kt <= ta) process(qA, oA, mA, lA, ta, kt, Kst, Vst);
    process(qB, oB, mB, lB, tb, kt, Kst, Vst);
  }

  // epilogue: normalize and write ctx [(s*B+b)][h*128+d]
  const int b = bh >> 4;
  const int h = bh & 15;
#pragma unroll
  for (int df = 0; df < 8; ++df) {
    int dd = df * 16 + (l & 15);
#pragma unroll
    for (int r = 0; r < 4; ++r) {
      int sA = ta * 64 + w * 16 + (l >> 4) * 4 + r;
      ctx[((size_t)(sA * BATCH + b)) * HID + h * HD + dd] = (_Float16)(oA[df][r] / lA[r]);
      int sB = tb * 64 + w * 16 + (l >> 4) * 4 + r;
      ctx[((size_t)(sB * BATCH + b)) * HID + h * HD + dd] = (_Float16)(oB[df][r] / lB[r]);
    }
  }
}

// ---------------------------------------------------------------------------

extern "C" void kernel_launch(void* const* d_in, const int* in_sizes, int n_in,
                              void* d_out, int out_size, void* d_ws, size_t ws_size,
                              hipStream_t stream) {
  const float* x = (const float*)d_in[0];
  const float* w_qkv = (const float*)d_in[1];
  const float* w_dense = (const float*)d_in[2];
  float* out = (float*)d_out;
  char* ws = (char*)d_ws;

  _Float16* xb    = (_Float16*)(ws);               // 4096x2048        16 MB
  _Float16* wqkvT = (_Float16*)(ws + 16777216);    // 6144x2048        24 MB
  _Float16* wdT   = (_Float16*)(ws + 41943040);    // 2048x2048         8 MB
  _Float16* Qb    = (_Float16*)(ws + 50331648);    // [32][2048][128]  16 MB
  _Float16* Kb    = (_Float16*)(ws + 67108864);    // [32][2048][128]  16 MB
  _Float16* Vb    = (_Float16*)(ws + 83886080);    // [32][2048][128]  16 MB
  _Float16* VTb   = (_Float16*)(ws + 100663296);   // [32][128][2048]  16 MB
  _Float16* ctx   = (_Float16*)(ws + 117440512);   // 4096x2048        16 MB
  float* cost     = (float*)(ws + 134217728);      // 2048x64 fp32
  float* sint     = (float*)(ws + 134742016);      // 2048x64 fp32

  cast_x_kernel<<<dim3(8192), dim3(256), 0, stream>>>(x, xb, 2097152);
  transpose_cast_kernel<<<dim3(192, 64), dim3(32, 8), 0, stream>>>(w_qkv, wqkvT, 2048, 6144);
  transpose_cast_kernel<<<dim3(64, 64), dim3(32, 8), 0, stream>>>(w_dense, wdT, 2048, 2048);
  rope_table_kernel<<<dim3(2048), dim3(64), 0, stream>>>(cost, sint);

  gemm_kernel<0><<<dim3(1536), dim3(256), 0, stream>>>(xb, wqkvT, 4096, 6144, 2048, 32,
                                                       Qb, Kb, Vb, (float*)nullptr);
  rope_apply_kernel<<<dim3(16384), dim3(256), 0, stream>>>(Qb, Kb, cost, sint);
  transpose_v_kernel<<<dim3(64, 4, 32), dim3(32, 8), 0, stream>>>(Vb, VTb);
  attn_kernel<<<dim3(512), dim3(256), 0, stream>>>(Qb, Kb, VTb, ctx);
  gemm_kernel<1><<<dim3(512), dim3(256), 0, stream>>>(ctx, wdT, 4096, 2048, 2048, 32,
                                                      (_Float16*)nullptr, (_Float16*)nullptr,
                                                      (_Float16*)nullptr, out);
}